// Round 1
// baseline (530.699 us; speedup 1.0000x reference)
//
#include <hip/hip_runtime.h>

#define D 96        // D_IN == D_OUT
#define ROWPAD 97   // +1 pad breaks 96-stride LDS bank aliasing (96 % 32 == 0)

// ---------------------------------------------------------------------------
// Phase 1: edge scatter. One thread per (edge, feature). 76.8M fp32 atomics.
// Lanes within a wave cover consecutive features of 1-2 edges -> coalesced
// gather reads of x[src] (384 B rows). deg counted by the d==0 thread.
// ---------------------------------------------------------------------------
__global__ __launch_bounds__(256) void scatter_kernel(
    const float* __restrict__ x,
    const int* __restrict__ src,
    const int* __restrict__ dst,
    float* __restrict__ agg,
    float* __restrict__ deg,
    int E)
{
    int t = blockIdx.x * blockDim.x + threadIdx.x;
    int e = t / D;
    if (e >= E) return;
    int d = t - e * D;
    int s  = src[e];
    int dd = dst[e];
    atomicAdd(&agg[dd * D + d], x[s * D + d]);
    if (d == 0) atomicAdd(&deg[dd], 1.0f);
}

// ---------------------------------------------------------------------------
// Phase 2: out = relu((agg/max(deg,1)) @ Wl^T + bl + x @ Wr^T)
// Block = 256 threads handles 16 nodes (50000 = 3125 * 16 exactly).
// W staged in LDS one matrix at a time (two passes) to stay < 64 KB static
// LDS: 96*97*4 + 16*97*4 = 43.5 KB -> 2+ blocks/CU.
// Compute mapping j = tid + k*256 -> (node_local = j/96, o = j%96):
// consecutive threads read W_s at stride ROWPAD=97 -> conflict-free;
// rows[] read is wave-broadcast (same node_local for ~a whole wave).
// ---------------------------------------------------------------------------
__global__ __launch_bounds__(256) void fused_gemm(
    const float* __restrict__ x,
    const float* __restrict__ agg,
    const float* __restrict__ deg,
    const float* __restrict__ Wl,
    const float* __restrict__ bl,
    const float* __restrict__ Wr,
    float* __restrict__ out,
    int N)
{
    __shared__ float W_s[D * ROWPAD];
    __shared__ float rows[16 * ROWPAD];
    const int tid   = threadIdx.x;
    const int node0 = blockIdx.x * 16;
    float acc[6];

    // ---- pass 1: acc = (agg/deg) . Wl^T ----
    for (int i = tid; i < D * D; i += 256) {
        int o = i / D, dd = i - o * D;
        W_s[o * ROWPAD + dd] = Wl[i];
    }
    for (int i = tid; i < 16 * D; i += 256) {
        int il = i / D, dd = i - il * D;
        int node = node0 + il;
        float v = 0.0f;
        if (node < N) {
            float dg = deg[node];
            v = agg[node * D + dd] * (1.0f / fmaxf(dg, 1.0f));
        }
        rows[il * ROWPAD + dd] = v;
    }
    __syncthreads();
    #pragma unroll
    for (int k = 0; k < 6; ++k) {
        int j = tid + k * 256;
        int il = j / D, o = j - il * D;
        float a = 0.0f;
        #pragma unroll
        for (int dd = 0; dd < D; ++dd)
            a = fmaf(rows[il * ROWPAD + dd], W_s[o * ROWPAD + dd], a);
        acc[k] = a;
    }
    __syncthreads();

    // ---- pass 2: acc += x . Wr^T, then bias + relu + store ----
    for (int i = tid; i < D * D; i += 256) {
        int o = i / D, dd = i - o * D;
        W_s[o * ROWPAD + dd] = Wr[i];
    }
    for (int i = tid; i < 16 * D; i += 256) {
        int il = i / D, dd = i - il * D;
        int node = node0 + il;
        rows[il * ROWPAD + dd] = (node < N) ? x[node * D + dd] : 0.0f;
    }
    __syncthreads();
    #pragma unroll
    for (int k = 0; k < 6; ++k) {
        int j = tid + k * 256;
        int il = j / D, o = j - il * D;
        float a = acc[k];
        #pragma unroll
        for (int dd = 0; dd < D; ++dd)
            a = fmaf(rows[il * ROWPAD + dd], W_s[o * ROWPAD + dd], a);
        int node = node0 + il;
        if (node < N)
            out[node * D + o] = fmaxf(a + bl[o], 0.0f);
    }
}

extern "C" void kernel_launch(void* const* d_in, const int* in_sizes, int n_in,
                              void* d_out, int out_size, void* d_ws, size_t ws_size,
                              hipStream_t stream)
{
    const float* x  = (const float*)d_in[0];
    const int*   ei = (const int*)d_in[1];   // [2, E] flat: src row then dst row
    const float* Wl = (const float*)d_in[2];
    const float* bl = (const float*)d_in[3];
    const float* Wr = (const float*)d_in[4];
    float* out = (float*)d_out;

    const int N = in_sizes[0] / D;   // 50000
    const int E = in_sizes[1] / 2;   // 800000
    const int* src = ei;
    const int* dst = ei + E;

    // workspace: agg [N*96] fp32, then deg [N] fp32  (~19.4 MB)
    float* agg = (float*)d_ws;
    float* deg = agg + (size_t)N * D;
    hipMemsetAsync(d_ws, 0, ((size_t)N * D + N) * sizeof(float), stream);

    int total = E * D;                       // 76.8M threads
    int sblocks = (total + 255) / 256;
    scatter_kernel<<<sblocks, 256, 0, stream>>>(x, src, dst, agg, deg, E);

    int gblocks = (N + 15) / 16;             // 3125
    fused_gemm<<<gblocks, 256, 0, stream>>>(x, agg, deg, Wl, bl, Wr, out, N);
}

// Round 2
// 517.340 us; speedup vs baseline: 1.0258x; 1.0258x over previous
//
#include <hip/hip_runtime.h>

#define D 96
#define NN 50000
#define S100 100   // padded row stride in floats (mult of 4 for float4; 100%32=4 -> 4-deep banks)
#define S4 25      // stride in float4

// ---------------------------------------------------------------------------
// CSR build phase: counts -> exclusive scan -> bucket fill. Int atomics only.
// ---------------------------------------------------------------------------
__global__ __launch_bounds__(256) void hist_kernel(
    const int* __restrict__ dst, int* __restrict__ counts, int E)
{
    int e = blockIdx.x * 256 + threadIdx.x;
    if (e < E) atomicAdd(&counts[dst[e]], 1);
}

// Single-block hierarchical scan (wave shfl scan + cross-wave LDS), 1024 thr.
__global__ __launch_bounds__(1024) void scan_kernel(
    const int* __restrict__ counts, int* __restrict__ rowptr,
    int* __restrict__ cursor, int N)
{
    __shared__ int wsum[16];
    __shared__ int carry;
    const int tid = threadIdx.x;
    const int lane = tid & 63, wid = tid >> 6;
    if (tid == 0) carry = 0;
    __syncthreads();
    for (int base = 0; base < N; base += 1024) {
        int idx = base + tid;
        int v = (idx < N) ? counts[idx] : 0;
        int s = v;
        #pragma unroll
        for (int off = 1; off < 64; off <<= 1) {
            int t = __shfl_up(s, off);
            if (lane >= off) s += t;
        }
        if (lane == 63) wsum[wid] = s;
        __syncthreads();
        if (wid == 0) {
            int w = (lane < 16) ? wsum[lane] : 0;
            #pragma unroll
            for (int off = 1; off < 16; off <<= 1) {
                int t = __shfl_up(w, off);
                if (lane >= off) w += t;
            }
            if (lane < 16) wsum[lane] = w;
        }
        __syncthreads();
        int woff = (wid > 0) ? wsum[wid - 1] : 0;
        int excl = carry + woff + s - v;
        if (idx < N) { rowptr[idx] = excl; cursor[idx] = excl; }
        int total = wsum[15];
        __syncthreads();                 // all reads of carry/wsum done
        if (tid == 0) carry += total;
        __syncthreads();
    }
    if (tid == 0) rowptr[N] = carry;     // == E
}

__global__ __launch_bounds__(256) void fill_kernel(
    const int* __restrict__ src, const int* __restrict__ dst,
    int* __restrict__ cursor, int* __restrict__ csr_src, int E)
{
    int e = blockIdx.x * 256 + threadIdx.x;
    if (e < E) {
        int d = dst[e];
        int pos = atomicAdd(&cursor[d], 1);
        csr_src[pos] = src[e];
    }
}

// ---------------------------------------------------------------------------
// Aggregation as gather: 128 threads per node (2 nodes / 256-block), so wave
// trip counts are node-uniform (waves 0-1 -> node A, 2-3 -> node B).
// Writes mean-normalized agg. No atomics.
// ---------------------------------------------------------------------------
__global__ __launch_bounds__(256) void agg_kernel(
    const float* __restrict__ x, const int* __restrict__ rowptr,
    const int* __restrict__ csr_src, float* __restrict__ agg, int N)
{
    int node = blockIdx.x * 2 + (threadIdx.x >> 7);
    int dd = threadIdx.x & 127;
    if (node >= N || dd >= D) return;
    int beg = rowptr[node], end = rowptr[node + 1];
    float acc = 0.0f;
    for (int j = beg; j < end; ++j) {
        int s = csr_src[j];
        acc += x[(size_t)s * D + dd];
    }
    float inv = 1.0f / fmaxf((float)(end - beg), 1.0f);
    agg[(size_t)node * D + dd] = acc * inv;
}

// ---------------------------------------------------------------------------
// out = relu(agg @ Wl^T + bl + x @ Wr^T), 16 nodes/block, 256 threads.
// Per-thread 2x3 register tile (2 nodes x outs {oc, oc+32, oc+64}), float4
// LDS reads: 5 ds_read_b128 per 24 FMA. rows reads are wave-broadcast
// (2 addrs/wave); W reads land 4-deep per bank (stride 100 floats).
// LDS: (96+16)*100*4 = 44.8 KB -> 3 blocks/CU.
// ---------------------------------------------------------------------------
__global__ __launch_bounds__(256) void fused_gemm(
    const float* __restrict__ x,
    const float* __restrict__ agg,
    const float* __restrict__ Wl,
    const float* __restrict__ bl,
    const float* __restrict__ Wr,
    float* __restrict__ out,
    int N)
{
    __shared__ float4 Wbuf[D * S4];
    __shared__ float4 Rbuf[16 * S4];
    float* Ws = (float*)Wbuf;
    float* Rs = (float*)Rbuf;

    const int tid = threadIdx.x;
    const int node0 = blockIdx.x * 16;
    const int oc = tid & 31;          // output col group: o = oc + 32j
    const int il0 = (tid >> 5) * 2;   // node pair within block
    float acc[6] = {0.f, 0.f, 0.f, 0.f, 0.f, 0.f};

    // ---- pass 1: agg . Wl^T ----
    for (int i = tid; i < D * D; i += 256) {
        int o = i / D, d = i - o * D;
        Ws[o * S100 + d] = Wl[i];
    }
    for (int i = tid; i < 16 * D; i += 256) {
        int il = i / D, d = i - il * D;
        Rs[il * S100 + d] = agg[(size_t)(node0 + il) * D + d];
    }
    __syncthreads();
    #pragma unroll
    for (int k = 0; k < S4 - 1; ++k) {   // 24 float4 groups = 96 features
        float4 r0 = Rbuf[il0 * S4 + k];
        float4 r1 = Rbuf[(il0 + 1) * S4 + k];
        float4 w0 = Wbuf[oc * S4 + k];
        float4 w1 = Wbuf[(oc + 32) * S4 + k];
        float4 w2 = Wbuf[(oc + 64) * S4 + k];
        acc[0] += r0.x*w0.x + r0.y*w0.y + r0.z*w0.z + r0.w*w0.w;
        acc[1] += r0.x*w1.x + r0.y*w1.y + r0.z*w1.z + r0.w*w1.w;
        acc[2] += r0.x*w2.x + r0.y*w2.y + r0.z*w2.z + r0.w*w2.w;
        acc[3] += r1.x*w0.x + r1.y*w0.y + r1.z*w0.z + r1.w*w0.w;
        acc[4] += r1.x*w1.x + r1.y*w1.y + r1.z*w1.z + r1.w*w1.w;
        acc[5] += r1.x*w2.x + r1.y*w2.y + r1.z*w2.z + r1.w*w2.w;
    }
    __syncthreads();

    // ---- pass 2: + x . Wr^T ----
    for (int i = tid; i < D * D; i += 256) {
        int o = i / D, d = i - o * D;
        Ws[o * S100 + d] = Wr[i];
    }
    for (int i = tid; i < 16 * D; i += 256) {
        int il = i / D, d = i - il * D;
        Rs[il * S100 + d] = x[(size_t)(node0 + il) * D + d];
    }
    __syncthreads();
    #pragma unroll
    for (int k = 0; k < S4 - 1; ++k) {
        float4 r0 = Rbuf[il0 * S4 + k];
        float4 r1 = Rbuf[(il0 + 1) * S4 + k];
        float4 w0 = Wbuf[oc * S4 + k];
        float4 w1 = Wbuf[(oc + 32) * S4 + k];
        float4 w2 = Wbuf[(oc + 64) * S4 + k];
        acc[0] += r0.x*w0.x + r0.y*w0.y + r0.z*w0.z + r0.w*w0.w;
        acc[1] += r0.x*w1.x + r0.y*w1.y + r0.z*w1.z + r0.w*w1.w;
        acc[2] += r0.x*w2.x + r0.y*w2.y + r0.z*w2.z + r0.w*w2.w;
        acc[3] += r1.x*w0.x + r1.y*w0.y + r1.z*w0.z + r1.w*w0.w;
        acc[4] += r1.x*w1.x + r1.y*w1.y + r1.z*w1.z + r1.w*w1.w;
        acc[5] += r1.x*w2.x + r1.y*w2.y + r1.z*w2.z + r1.w*w2.w;
    }

    // ---- epilogue: bias + relu + store (coalesced: lane oc -> col oc+32j) ----
    #pragma unroll
    for (int r = 0; r < 2; ++r) {
        int node = node0 + il0 + r;
        #pragma unroll
        for (int j = 0; j < 3; ++j) {
            int o = oc + 32 * j;
            float v = acc[r * 3 + j] + bl[o];
            out[(size_t)node * D + o] = fmaxf(v, 0.0f);
        }
    }
}

extern "C" void kernel_launch(void* const* d_in, const int* in_sizes, int n_in,
                              void* d_out, int out_size, void* d_ws, size_t ws_size,
                              hipStream_t stream)
{
    const float* x  = (const float*)d_in[0];
    const int*   ei = (const int*)d_in[1];   // [2, E]: src row then dst row
    const float* Wl = (const float*)d_in[2];
    const float* bl = (const float*)d_in[3];
    const float* Wr = (const float*)d_in[4];
    float* out = (float*)d_out;

    const int N = in_sizes[0] / D;   // 50000
    const int E = in_sizes[1] / 2;   // 800000
    const int* src = ei;
    const int* dst = ei + E;

    // workspace layout (ints then floats), ~23 MB total
    int* counts  = (int*)d_ws;                 // [N]
    int* rowptr  = counts + N;                 // [N+1]
    int* cursor  = rowptr + (N + 1);           // [N]
    int* csr_src = cursor + N;                 // [E]
    float* agg   = (float*)(csr_src + E);      // [N*D]

    // only counts needs zero-init (ws is poisoned 0xAA each launch)
    hipMemsetAsync(counts, 0, (size_t)N * sizeof(int), stream);

    int eblocks = (E + 255) / 256;
    hist_kernel<<<eblocks, 256, 0, stream>>>(dst, counts, E);
    scan_kernel<<<1, 1024, 0, stream>>>(counts, rowptr, cursor, N);
    fill_kernel<<<eblocks, 256, 0, stream>>>(src, dst, cursor, csr_src, E);

    int ablocks = (N + 1) / 2;
    agg_kernel<<<ablocks, 256, 0, stream>>>(x, rowptr, csr_src, agg, N);

    int gblocks = (N + 15) / 16;     // 3125, exact
    fused_gemm<<<gblocks, 256, 0, stream>>>(x, agg, Wl, bl, Wr, out, N);
}

// Round 3
// 284.152 us; speedup vs baseline: 1.8677x; 1.8206x over previous
//
#include <hip/hip_runtime.h>
#include <hip/hip_bf16.h>

#define D 96
#define S4 25     // padded row stride in float4 (=100 floats; uniform bank coverage)

// ---------------------------------------------------------------------------
// CSR build: hist -> (reduce, scan-partials, block-scan) -> fill. Int atomics.
// ---------------------------------------------------------------------------
__global__ __launch_bounds__(256) void hist_kernel(
    const int* __restrict__ dst, int* __restrict__ counts, int E)
{
    int e = blockIdx.x * 256 + threadIdx.x;
    if (e < E) atomicAdd(&counts[dst[e]], 1);
}

__global__ __launch_bounds__(256) void scan_reduce(
    const int* __restrict__ counts, int* __restrict__ partials, int N)
{
    __shared__ int ws[4];
    int lane = threadIdx.x & 63, wid = threadIdx.x >> 6;
    int idx = blockIdx.x * 256 + threadIdx.x;
    int v = (idx < N) ? counts[idx] : 0;
    #pragma unroll
    for (int off = 32; off > 0; off >>= 1) v += __shfl_down(v, off);
    if (lane == 0) ws[wid] = v;
    __syncthreads();
    if (threadIdx.x == 0) partials[blockIdx.x] = ws[0] + ws[1] + ws[2] + ws[3];
}

// single block scans <=256 partials in place (exclusive); writes rowptr[N]=E
__global__ __launch_bounds__(256) void scan_partials(
    int* __restrict__ partials, int* __restrict__ rowptr, int NB, int N)
{
    __shared__ int wsum[4];
    int tid = threadIdx.x, lane = tid & 63, wid = tid >> 6;
    int v = (tid < NB) ? partials[tid] : 0;
    int s = v;
    #pragma unroll
    for (int off = 1; off < 64; off <<= 1) {
        int t = __shfl_up(s, off);
        if (lane >= off) s += t;
    }
    if (lane == 63) wsum[wid] = s;
    __syncthreads();
    int woff = 0;
    for (int w = 0; w < wid; ++w) woff += wsum[w];
    if (tid < NB) partials[tid] = woff + s - v;   // exclusive
    if (tid == 255) rowptr[N] = woff + s;         // total == E
}

__global__ __launch_bounds__(256) void scan_blocks(
    const int* __restrict__ counts, const int* __restrict__ partials,
    int* __restrict__ rowptr, int* __restrict__ cursor, int N)
{
    __shared__ int wsum[4];
    int tid = threadIdx.x, lane = tid & 63, wid = tid >> 6;
    int idx = blockIdx.x * 256 + tid;
    int v = (idx < N) ? counts[idx] : 0;
    int s = v;
    #pragma unroll
    for (int off = 1; off < 64; off <<= 1) {
        int t = __shfl_up(s, off);
        if (lane >= off) s += t;
    }
    if (lane == 63) wsum[wid] = s;
    __syncthreads();
    int woff = partials[blockIdx.x];
    for (int w = 0; w < wid; ++w) woff += wsum[w];
    int excl = woff + s - v;
    if (idx < N) { rowptr[idx] = excl; cursor[idx] = excl; }
}

__global__ __launch_bounds__(256) void fill_kernel(
    const int* __restrict__ src, const int* __restrict__ dst,
    int* __restrict__ cursor, int* __restrict__ csr_src, int E)
{
    int e = blockIdx.x * 256 + threadIdx.x;
    if (e < E) {
        int pos = atomicAdd(&cursor[dst[e]], 1);
        csr_src[pos] = src[e];
    }
}

// ---------------------------------------------------------------------------
// GEMM: hl = x @ Wl^T (bf16 -> ws), hr = x @ Wr^T (fp32 -> d_out).
// 16 nodes/block, 256 thr, 2 nodes x 3 cols per thread. x-tile staged once;
// W staged per pass. unroll 2 keeps VGPR ~<100 (round-2 full unroll hit 256).
// ---------------------------------------------------------------------------
__global__ __launch_bounds__(256, 4) void gemm_kernel(
    const float* __restrict__ x, const float* __restrict__ Wl,
    const float* __restrict__ Wr, __hip_bfloat16* __restrict__ hl,
    float* __restrict__ hr, int N)
{
    __shared__ float4 Wbuf[D * S4];
    __shared__ float4 Rbuf[16 * S4];
    const int tid = threadIdx.x;
    const int node0 = blockIdx.x * 16;   // 3125 * 16 == 50000 exactly
    const int oc = tid & 31;
    const int il0 = (tid >> 5) * 2;

    const float4* x4 = (const float4*)x;
    for (int i = tid; i < 16 * 24; i += 256) {
        int il = i / 24, q = i - il * 24;
        Rbuf[il * S4 + q] = x4[(size_t)(node0 + il) * 24 + q];
    }
    const float4* wl4 = (const float4*)Wl;
    for (int i = tid; i < D * 24; i += 256) {
        int o = i / 24, q = i - o * 24;
        Wbuf[o * S4 + q] = wl4[i];
    }
    __syncthreads();

    float acc[6] = {0.f, 0.f, 0.f, 0.f, 0.f, 0.f};
    #pragma unroll 2
    for (int k = 0; k < 24; ++k) {
        float4 r0 = Rbuf[il0 * S4 + k];
        float4 r1 = Rbuf[(il0 + 1) * S4 + k];
        float4 w0 = Wbuf[oc * S4 + k];
        float4 w1 = Wbuf[(oc + 32) * S4 + k];
        float4 w2 = Wbuf[(oc + 64) * S4 + k];
        acc[0] += r0.x*w0.x + r0.y*w0.y + r0.z*w0.z + r0.w*w0.w;
        acc[1] += r0.x*w1.x + r0.y*w1.y + r0.z*w1.z + r0.w*w1.w;
        acc[2] += r0.x*w2.x + r0.y*w2.y + r0.z*w2.z + r0.w*w2.w;
        acc[3] += r1.x*w0.x + r1.y*w0.y + r1.z*w0.z + r1.w*w0.w;
        acc[4] += r1.x*w1.x + r1.y*w1.y + r1.z*w1.z + r1.w*w1.w;
        acc[5] += r1.x*w2.x + r1.y*w2.y + r1.z*w2.z + r1.w*w2.w;
    }
    #pragma unroll
    for (int r = 0; r < 2; ++r) {
        int node = node0 + il0 + r;
        #pragma unroll
        for (int j = 0; j < 3; ++j)
            hl[(size_t)node * D + oc + 32 * j] = __float2bfloat16(acc[r * 3 + j]);
    }
    __syncthreads();

    const float4* wr4 = (const float4*)Wr;
    for (int i = tid; i < D * 24; i += 256) {
        int o = i / 24, q = i - o * 24;
        Wbuf[o * S4 + q] = wr4[i];
    }
    __syncthreads();

    float acc2[6] = {0.f, 0.f, 0.f, 0.f, 0.f, 0.f};
    #pragma unroll 2
    for (int k = 0; k < 24; ++k) {
        float4 r0 = Rbuf[il0 * S4 + k];
        float4 r1 = Rbuf[(il0 + 1) * S4 + k];
        float4 w0 = Wbuf[oc * S4 + k];
        float4 w1 = Wbuf[(oc + 32) * S4 + k];
        float4 w2 = Wbuf[(oc + 64) * S4 + k];
        acc2[0] += r0.x*w0.x + r0.y*w0.y + r0.z*w0.z + r0.w*w0.w;
        acc2[1] += r0.x*w1.x + r0.y*w1.y + r0.z*w1.z + r0.w*w1.w;
        acc2[2] += r0.x*w2.x + r0.y*w2.y + r0.z*w2.z + r0.w*w2.w;
        acc2[3] += r1.x*w0.x + r1.y*w0.y + r1.z*w0.z + r1.w*w0.w;
        acc2[4] += r1.x*w1.x + r1.y*w1.y + r1.z*w1.z + r1.w*w1.w;
        acc2[5] += r1.x*w2.x + r1.y*w2.y + r1.z*w2.z + r1.w*w2.w;
    }
    #pragma unroll
    for (int r = 0; r < 2; ++r) {
        int node = node0 + il0 + r;
        #pragma unroll
        for (int j = 0; j < 3; ++j)
            hr[(size_t)node * D + oc + 32 * j] = acc2[r * 3 + j];
    }
}

// ---------------------------------------------------------------------------
// Fused gather-mean + bias + relu. One wave per node (trip count uniform per
// wave). Lane l<48 handles features {2l, 2l+1} as one bf16x2 (uint) load.
// out already holds hr (fp32); finish in place.
// ---------------------------------------------------------------------------
__device__ __forceinline__ float bf_lo(unsigned p) { return __uint_as_float(p << 16); }
__device__ __forceinline__ float bf_hi(unsigned p) { return __uint_as_float(p & 0xFFFF0000u); }

__global__ __launch_bounds__(256) void agg_out_kernel(
    const __hip_bfloat16* __restrict__ hl, const int* __restrict__ rowptr,
    const int* __restrict__ csr_src, const float* __restrict__ bl,
    float* __restrict__ out, int N)
{
    int lane = threadIdx.x & 63;
    int node = blockIdx.x * 4 + (threadIdx.x >> 6);
    if (node >= N) return;
    int beg = rowptr[node], end = rowptr[node + 1];
    bool active = lane < 48;
    float a0 = 0.f, a1 = 0.f;
    int j = beg;
    for (; j + 2 <= end; j += 2) {
        int s0 = csr_src[j];
        int s1 = csr_src[j + 1];
        if (active) {
            unsigned p0 = *(const unsigned*)((const char*)hl + (size_t)s0 * 192 + lane * 4);
            unsigned p1 = *(const unsigned*)((const char*)hl + (size_t)s1 * 192 + lane * 4);
            a0 += bf_lo(p0) + bf_lo(p1);
            a1 += bf_hi(p0) + bf_hi(p1);
        }
    }
    if (j < end) {
        int s0 = csr_src[j];
        if (active) {
            unsigned p0 = *(const unsigned*)((const char*)hl + (size_t)s0 * 192 + lane * 4);
            a0 += bf_lo(p0);
            a1 += bf_hi(p0);
        }
    }
    if (active) {
        float inv = 1.0f / fmaxf((float)(end - beg), 1.0f);
        int o = 2 * lane;
        size_t base = (size_t)node * D + o;
        float v0 = a0 * inv + bl[o]     + out[base];
        float v1 = a1 * inv + bl[o + 1] + out[base + 1];
        out[base]     = fmaxf(v0, 0.f);
        out[base + 1] = fmaxf(v1, 0.f);
    }
}

extern "C" void kernel_launch(void* const* d_in, const int* in_sizes, int n_in,
                              void* d_out, int out_size, void* d_ws, size_t ws_size,
                              hipStream_t stream)
{
    const float* x  = (const float*)d_in[0];
    const int*   ei = (const int*)d_in[1];   // [2, E]: src row then dst row
    const float* Wl = (const float*)d_in[2];
    const float* bl = (const float*)d_in[3];
    const float* Wr = (const float*)d_in[4];
    float* out = (float*)d_out;

    const int N = in_sizes[0] / D;   // 50000
    const int E = in_sizes[1] / 2;   // 800000
    const int* src = ei;
    const int* dst = ei + E;

    // ws layout: ints then bf16 hl  (~13.4 MB total)
    int* counts   = (int*)d_ws;                    // [N]
    int* rowptr   = counts + N;                    // [N+1]
    int* cursor   = rowptr + (N + 1);              // [N]
    int* csr_src  = cursor + N;                    // [E]
    int* partials = csr_src + E;                   // [256]
    __hip_bfloat16* hl = (__hip_bfloat16*)(partials + 256);  // [N*D]

    hipMemsetAsync(counts, 0, (size_t)N * sizeof(int), stream);

    const int eblocks = (E + 255) / 256;           // 3125
    const int nblocks = (N + 255) / 256;           // 196

    hist_kernel  <<<eblocks, 256, 0, stream>>>(dst, counts, E);
    scan_reduce  <<<nblocks, 256, 0, stream>>>(counts, partials, N);
    scan_partials<<<1,       256, 0, stream>>>(partials, rowptr, nblocks, N);
    scan_blocks  <<<nblocks, 256, 0, stream>>>(counts, partials, rowptr, cursor, N);
    fill_kernel  <<<eblocks, 256, 0, stream>>>(src, dst, cursor, csr_src, E);

    gemm_kernel<<<N / 16, 256, 0, stream>>>(x, Wl, Wr, hl, out, N);

    agg_out_kernel<<<(N + 3) / 4, 256, 0, stream>>>(hl, rowptr, csr_src, bl, out, N);
}

// Round 4
// 260.595 us; speedup vs baseline: 2.0365x; 1.0904x over previous
//
#include <hip/hip_runtime.h>
#include <hip/hip_bf16.h>

#define D 96

typedef __attribute__((ext_vector_type(8))) short bf16x8;  // 8 bf16 (4 VGPRs)
typedef __attribute__((ext_vector_type(4))) float f32x4;

// ---------------------------------------------------------------------------
// CSR build: hist -> alloc (block scan + one atomic per block; bucket order
// across blocks is arbitrary, which CSR doesn't care about) -> fill.
// ---------------------------------------------------------------------------
__global__ __launch_bounds__(256) void hist_kernel(
    const int* __restrict__ dst, int* __restrict__ counts, int E)
{
    int e = blockIdx.x * 256 + threadIdx.x;
    if (e < E) atomicAdd(&counts[dst[e]], 1);
}

__global__ __launch_bounds__(256) void alloc_kernel(
    const int* __restrict__ counts, int* __restrict__ beg,
    int* __restrict__ cursor, int* __restrict__ gcursor, int N)
{
    __shared__ int wsum[4];
    __shared__ int base_s;
    int tid = threadIdx.x, lane = tid & 63, wid = tid >> 6;
    int idx = blockIdx.x * 256 + tid;
    int v = (idx < N) ? counts[idx] : 0;
    int s = v;
    #pragma unroll
    for (int off = 1; off < 64; off <<= 1) {
        int t = __shfl_up(s, off);
        if (lane >= off) s += t;
    }
    if (lane == 63) wsum[wid] = s;
    __syncthreads();
    if (tid == 0)
        base_s = atomicAdd(gcursor, wsum[0] + wsum[1] + wsum[2] + wsum[3]);
    __syncthreads();
    int woff = 0;
    for (int w = 0; w < wid; ++w) woff += wsum[w];
    int excl = woff + s - v;                 // block-exclusive prefix
    if (idx < N) {
        int b = base_s + excl;
        beg[idx] = b;
        cursor[idx] = b;
    }
}

__global__ __launch_bounds__(256) void fill_kernel(
    const int* __restrict__ src, const int* __restrict__ dst,
    int* __restrict__ cursor, int* __restrict__ csr_src, int E)
{
    int e = blockIdx.x * 256 + threadIdx.x;
    if (e < E) {
        int pos = atomicAdd(&cursor[dst[e]], 1);
        csr_src[pos] = src[e];
    }
}

// ---------------------------------------------------------------------------
// MFMA GEMM, no LDS: hl = x @ Wl^T (bf16 -> ws), hr = x @ Wr^T (fp32 -> out).
// One wave per 16-row tile; K=96 = 3 MFMA k-steps held in registers.
// Verified layouts (m89/m120): A[m=lane&15][k=quad*8+j]; B^T rows load with
// the identical pattern; C/D col=lane&15, row=quad*4+reg.
// ---------------------------------------------------------------------------
__device__ __forceinline__ short f2bf(float f)
{
    __hip_bfloat16 h = __float2bfloat16(f);
    union { __hip_bfloat16 h; short s; } u;
    u.h = h;
    return u.s;
}

__device__ __forceinline__ bf16x8 load_frag(const float* p)
{
    float4 lo = *(const float4*)p;
    float4 hi = *(const float4*)(p + 4);
    bf16x8 r;
    r[0] = f2bf(lo.x); r[1] = f2bf(lo.y); r[2] = f2bf(lo.z); r[3] = f2bf(lo.w);
    r[4] = f2bf(hi.x); r[5] = f2bf(hi.y); r[6] = f2bf(hi.z); r[7] = f2bf(hi.w);
    return r;
}

__global__ __launch_bounds__(256) void mfma_gemm(
    const float* __restrict__ x, const float* __restrict__ Wl,
    const float* __restrict__ Wr, __hip_bfloat16* __restrict__ hl,
    float* __restrict__ hr, int N)
{
    int gwave = (blockIdx.x * 256 + threadIdx.x) >> 6;  // row-tile id
    int nrt = N / 16;                                   // 3125 (exact)
    if (gwave >= nrt) return;
    int lane = threadIdx.x & 63;
    int m = lane & 15, quad = lane >> 4;
    int row = gwave * 16 + m;

    bf16x8 a[3];
    #pragma unroll
    for (int kt = 0; kt < 3; ++kt)
        a[kt] = load_frag(x + (size_t)row * D + kt * 32 + quad * 8);

    int orow = gwave * 16 + quad * 4;                   // D-row base
    #pragma unroll
    for (int ct = 0; ct < 6; ++ct) {
        int wrow = ct * 16 + m;                         // = output col n
        const float* pl = Wl + (size_t)wrow * D + quad * 8;
        const float* pr = Wr + (size_t)wrow * D + quad * 8;
        f32x4 accl = {0.f, 0.f, 0.f, 0.f};
        f32x4 accr = {0.f, 0.f, 0.f, 0.f};
        #pragma unroll
        for (int kt = 0; kt < 3; ++kt) {
            bf16x8 b = load_frag(pl + kt * 32);
            accl = __builtin_amdgcn_mfma_f32_16x16x32_bf16(a[kt], b, accl, 0, 0, 0);
        }
        #pragma unroll
        for (int kt = 0; kt < 3; ++kt) {
            bf16x8 b = load_frag(pr + kt * 32);
            accr = __builtin_amdgcn_mfma_f32_16x16x32_bf16(a[kt], b, accr, 0, 0, 0);
        }
        int col = ct * 16 + m;
        #pragma unroll
        for (int r = 0; r < 4; ++r) {
            hl[(size_t)(orow + r) * D + col] = __float2bfloat16(accl[r]);
            hr[(size_t)(orow + r) * D + col] = accr[r];
        }
    }
}

// ---------------------------------------------------------------------------
// Fused gather-mean + bias + relu. One wave per node; lane l<48 handles
// features {2l, 2l+1} as one packed-bf16 dword load. out holds hr; finish
// in place.
// ---------------------------------------------------------------------------
__device__ __forceinline__ float bf_lo(unsigned p) { return __uint_as_float(p << 16); }
__device__ __forceinline__ float bf_hi(unsigned p) { return __uint_as_float(p & 0xFFFF0000u); }

__global__ __launch_bounds__(256) void agg_out_kernel(
    const __hip_bfloat16* __restrict__ hl, const int* __restrict__ beg_arr,
    const int* __restrict__ counts, const int* __restrict__ csr_src,
    const float* __restrict__ bl, float* __restrict__ out, int N)
{
    int lane = threadIdx.x & 63;
    int node = blockIdx.x * 4 + (threadIdx.x >> 6);
    if (node >= N) return;
    int beg = beg_arr[node];
    int deg = counts[node];
    int end = beg + deg;
    bool active = lane < 48;
    float a0 = 0.f, a1 = 0.f;
    int j = beg;
    for (; j + 2 <= end; j += 2) {
        int s0 = csr_src[j];
        int s1 = csr_src[j + 1];
        if (active) {
            unsigned p0 = *(const unsigned*)((const char*)hl + (size_t)s0 * 192 + lane * 4);
            unsigned p1 = *(const unsigned*)((const char*)hl + (size_t)s1 * 192 + lane * 4);
            a0 += bf_lo(p0) + bf_lo(p1);
            a1 += bf_hi(p0) + bf_hi(p1);
        }
    }
    if (j < end) {
        int s0 = csr_src[j];
        if (active) {
            unsigned p0 = *(const unsigned*)((const char*)hl + (size_t)s0 * 192 + lane * 4);
            a0 += bf_lo(p0);
            a1 += bf_hi(p0);
        }
    }
    if (active) {
        float inv = 1.0f / fmaxf((float)deg, 1.0f);
        int o = 2 * lane;
        size_t base = (size_t)node * D + o;
        float v0 = a0 * inv + bl[o]     + out[base];
        float v1 = a1 * inv + bl[o + 1] + out[base + 1];
        out[base]     = fmaxf(v0, 0.f);
        out[base + 1] = fmaxf(v1, 0.f);
    }
}

extern "C" void kernel_launch(void* const* d_in, const int* in_sizes, int n_in,
                              void* d_out, int out_size, void* d_ws, size_t ws_size,
                              hipStream_t stream)
{
    const float* x  = (const float*)d_in[0];
    const int*   ei = (const int*)d_in[1];   // [2, E]: src row then dst row
    const float* Wl = (const float*)d_in[2];
    const float* bl = (const float*)d_in[3];
    const float* Wr = (const float*)d_in[4];
    float* out = (float*)d_out;

    const int N = in_sizes[0] / D;   // 50000
    const int E = in_sizes[1] / 2;   // 800000
    const int* src = ei;
    const int* dst = ei + E;

    // ws layout: counts[N], gcursor[1], beg[N], cursor[N], csr_src[E], hl[N*D] bf16
    int* counts  = (int*)d_ws;
    int* gcursor = counts + N;
    int* beg     = gcursor + 1;
    int* cursor  = beg + N;
    int* csr_src = cursor + N;
    __hip_bfloat16* hl = (__hip_bfloat16*)(csr_src + E);

    // zero counts + gcursor in one shot (contiguous)
    hipMemsetAsync(counts, 0, (size_t)(N + 1) * sizeof(int), stream);

    const int eblocks = (E + 255) / 256;     // 3125
    const int nblocks = (N + 255) / 256;     // 196

    hist_kernel <<<eblocks, 256, 0, stream>>>(dst, counts, E);
    alloc_kernel<<<nblocks, 256, 0, stream>>>(counts, beg, cursor, gcursor, N);
    fill_kernel <<<eblocks, 256, 0, stream>>>(src, dst, cursor, csr_src, E);

    const int gwaves  = N / 16;              // 3125 row tiles
    const int gblocks = (gwaves + 3) / 4;    // 4 waves/block
    mfma_gemm<<<gblocks, 256, 0, stream>>>(x, Wl, Wr, hl, out, N);

    agg_out_kernel<<<(N + 3) / 4, 256, 0, stream>>>(hl, beg, counts, csr_src, bl, out, N);
}